// Round 1
// baseline (202.070 us; speedup 1.0000x reference)
//
#include <hip/hip_runtime.h>

// Leave-one-out mean along dim 1.
// x: [ROWS, NCOLS] f32, out[b,i] = (row_sum[b] - x[b,i]) / (NCOLS - 1).
// One 1024-thread block per row; each thread holds 16 elements in registers
// (4x float4) so the row is read from HBM exactly once.

#define NCOLS 16384
#define BLOCK 1024
#define PER_THREAD_V4 4   // NCOLS / 4 / BLOCK

__global__ __launch_bounds__(BLOCK) void loo_mean_kernel(
    const float* __restrict__ x, float* __restrict__ out) {
    const int row = blockIdx.x;
    const float4* __restrict__ xr =
        reinterpret_cast<const float4*>(x + (size_t)row * NCOLS);
    float4* __restrict__ outr =
        reinterpret_cast<float4*>(out + (size_t)row * NCOLS);
    const int tid = threadIdx.x;

    float4 v[PER_THREAD_V4];
    float s = 0.0f;
#pragma unroll
    for (int i = 0; i < PER_THREAD_V4; ++i) {
        v[i] = xr[tid + i * BLOCK];
        s += (v[i].x + v[i].y) + (v[i].z + v[i].w);
    }

    // Wave-64 butterfly reduce
#pragma unroll
    for (int off = 32; off >= 1; off >>= 1)
        s += __shfl_down(s, off, 64);

    __shared__ float partial[BLOCK / 64];
    __shared__ float total_sh;
    const int wave = tid >> 6;
    const int lane = tid & 63;
    if (lane == 0) partial[wave] = s;
    __syncthreads();
    if (tid == 0) {
        float t = 0.0f;
#pragma unroll
        for (int w = 0; w < BLOCK / 64; ++w) t += partial[w];
        total_sh = t;
    }
    __syncthreads();

    const float total = total_sh;
    const float inv = 1.0f / (float)(NCOLS - 1);
#pragma unroll
    for (int i = 0; i < PER_THREAD_V4; ++i) {
        float4 o;
        o.x = (total - v[i].x) * inv;
        o.y = (total - v[i].y) * inv;
        o.z = (total - v[i].z) * inv;
        o.w = (total - v[i].w) * inv;
        outr[tid + i * BLOCK] = o;
    }
}

extern "C" void kernel_launch(void* const* d_in, const int* in_sizes, int n_in,
                              void* d_out, int out_size, void* d_ws, size_t ws_size,
                              hipStream_t stream) {
    const float* x = (const float*)d_in[0];
    float* out = (float*)d_out;
    const int rows = in_sizes[0] / NCOLS;  // 8192
    loo_mean_kernel<<<rows, BLOCK, 0, stream>>>(x, out);
}

// Round 2
// 185.065 us; speedup vs baseline: 1.0919x; 1.0919x over previous
//
#include <hip/hip_runtime.h>

// Leave-one-out mean along dim 1.
// x: [ROWS, NCOLS] f32, out[b,i] = (row_sum[b] - x[b,i]) / (NCOLS - 1).
// One 1024-thread block per row; each thread holds 16 elements in registers
// (4x float4) so the row is read from HBM exactly once.
// Round 2: nontemporal (streaming) loads+stores — x and out are touch-once,
// so bypass L2 allocation (`nt` flag on global_load/store_dwordx4).

#define NCOLS 16384
#define BLOCK 1024
#define PER_THREAD_V4 4   // NCOLS / 4 / BLOCK

using f32x4 = __attribute__((ext_vector_type(4))) float;

__global__ __launch_bounds__(BLOCK) void loo_mean_kernel(
    const float* __restrict__ x, float* __restrict__ out) {
    const int row = blockIdx.x;
    const f32x4* __restrict__ xr =
        reinterpret_cast<const f32x4*>(x + (size_t)row * NCOLS);
    f32x4* __restrict__ outr =
        reinterpret_cast<f32x4*>(out + (size_t)row * NCOLS);
    const int tid = threadIdx.x;

    f32x4 v[PER_THREAD_V4];
    float s = 0.0f;
#pragma unroll
    for (int i = 0; i < PER_THREAD_V4; ++i) {
        v[i] = __builtin_nontemporal_load(&xr[tid + i * BLOCK]);
        s += (v[i].x + v[i].y) + (v[i].z + v[i].w);
    }

    // Wave-64 butterfly reduce
#pragma unroll
    for (int off = 32; off >= 1; off >>= 1)
        s += __shfl_down(s, off, 64);

    __shared__ float partial[BLOCK / 64];
    __shared__ float total_sh;
    const int wave = tid >> 6;
    const int lane = tid & 63;
    if (lane == 0) partial[wave] = s;
    __syncthreads();
    if (tid == 0) {
        float t = 0.0f;
#pragma unroll
        for (int w = 0; w < BLOCK / 64; ++w) t += partial[w];
        total_sh = t;
    }
    __syncthreads();

    const float total = total_sh;
    const float inv = 1.0f / (float)(NCOLS - 1);
#pragma unroll
    for (int i = 0; i < PER_THREAD_V4; ++i) {
        f32x4 o;
        o.x = (total - v[i].x) * inv;
        o.y = (total - v[i].y) * inv;
        o.z = (total - v[i].z) * inv;
        o.w = (total - v[i].w) * inv;
        __builtin_nontemporal_store(o, &outr[tid + i * BLOCK]);
    }
}

extern "C" void kernel_launch(void* const* d_in, const int* in_sizes, int n_in,
                              void* d_out, int out_size, void* d_ws, size_t ws_size,
                              hipStream_t stream) {
    const float* x = (const float*)d_in[0];
    float* out = (float*)d_out;
    const int rows = in_sizes[0] / NCOLS;  // 8192
    loo_mean_kernel<<<rows, BLOCK, 0, stream>>>(x, out);
}